// Round 2
// baseline (3884.601 us; speedup 1.0000x reference)
//
#include <hip/hip_runtime.h>
#include <stdint.h>

// N=64, T=128, D=512, H=1024, 4H=4096.
// R7: exploit per-batch-row independence. 4 groups x 16 n-rows; each group
// served by 16 gemm wgs (wg = 64 hidden cols x 4 gates, one gate per wave,
// M=16 fills the MFMA). Fan-in is 16 sibling flags polled DIRECTLY --
// no aggregator, no mailboxes: 1 global hop per step instead of ~4.
//   - h tile 16x1024 staged to LDS with XOR swizzle ((n&7)<<3) ->
//     conflict-free ds_read_b128 A-fragments.
//   - Wh slice 512KB/wg re-read from L2 each step; wid=g*16+c => XCD=c%8
//     so the two c-aliased slices share an XCD (L2-resident).
//   - xwx re-laid out t-major [t][64][4096]: one contiguous slab per step.
//   - 16 score wgs unchanged math (f32 Af), poll group flags directly,
//     publish w + flag; consumed after GEMM (latency-hidden).
// Ordering discipline unchanged: relaxed agent data stores -> __syncthreads
// (vmcnt drain) -> relaxed flag; acquire fence on consumer side.
// Grid 80 (64 gemm + 16 score), 256 thr, 1 wg/CU.

#define Tt 128
#define FH 4096

typedef __bf16 bf8 __attribute__((ext_vector_type(8)));
typedef float f4 __attribute__((ext_vector_type(4)));
typedef short s8v __attribute__((ext_vector_type(8)));
typedef unsigned long long ull;

__device__ __forceinline__ float bf2f(unsigned short u) {
    union { unsigned u32; float f; } x; x.u32 = ((unsigned)u) << 16; return x.f;
}
__device__ __forceinline__ unsigned short f2bf(float f) {
    union { float f32; unsigned u; } x; x.f32 = f;
    unsigned r = x.u + 0x7fffu + ((x.u >> 16) & 1u);
    return (unsigned short)(r >> 16);
}
__device__ __forceinline__ ull ald(const ull* p) {
    return __hip_atomic_load((ull*)p, __ATOMIC_RELAXED, __HIP_MEMORY_SCOPE_AGENT);
}
__device__ __forceinline__ void ast(ull* p, ull v) {
    __hip_atomic_store(p, v, __ATOMIC_RELAXED, __HIP_MEMORY_SCOPE_AGENT);
}
__device__ __forceinline__ int aldi(const int* p) {
    return __hip_atomic_load((int*)p, __ATOMIC_RELAXED, __HIP_MEMORY_SCOPE_AGENT);
}
__device__ __forceinline__ void asti(int* p, int v) {
    __hip_atomic_store(p, v, __ATOMIC_RELAXED, __HIP_MEMORY_SCOPE_AGENT);
}

// ---------------- converts / init ----------------

__global__ __launch_bounds__(256) void k_cast_bf16(const float* __restrict__ in,
                                                   unsigned short* __restrict__ out, int n) {
    int i = blockIdx.x * 256 + threadIdx.x;
    if (i < n) out[i] = f2bf(in[i]);
}

__global__ __launch_bounds__(256) void k_transpose_bf16(const float* __restrict__ W,
                                                        unsigned short* __restrict__ WT, int K) {
    __shared__ float tl[32][33];
    int c0 = blockIdx.x * 32, k0 = blockIdx.y * 32;
    int tx = threadIdx.x & 31, ty = threadIdx.x >> 5;
    #pragma unroll
    for (int i = 0; i < 32; i += 8) tl[ty + i][tx] = W[(size_t)(k0 + ty + i) * 4096 + c0 + tx];
    __syncthreads();
    #pragma unroll
    for (int i = 0; i < 32; i += 8) WT[(size_t)(c0 + ty + i) * K + k0 + tx] = f2bf(tl[tx][ty + i]);
}

__global__ __launch_bounds__(256) void k_afl(const float* __restrict__ A,
                                             unsigned short* __restrict__ Afl) {
    int idx = blockIdx.x * 256 + threadIdx.x;
    int k = idx & 1023, l = (idx >> 10) & 15, n = idx >> 14;
    Afl[idx] = f2bf(A[((size_t)n * 1024 + k) * 16 + l]);
}

__global__ __launch_bounds__(256) void k_init(const float* __restrict__ A,
                                              float* __restrict__ cstate,
                                              unsigned short* __restrict__ hbf) {
    int idx = blockIdx.x * 256 + threadIdx.x;   // 64*1024
    const float* ap = A + (size_t)idx * 16;
    float s = 0.f;
    #pragma unroll
    for (int l = 0; l < 16; l++) s += ap[l];
    float h = s * (1.0f / 16.0f);
    cstate[idx] = h;
    hbf[idx] = f2bf(h);
}

// ---------------- generic bf16 MFMA GEMM (preamble) ----------------
// mode 0: out[row][col]           (row-major M x Nn)
// mode 1: out[n][col][l]          (row = n*16 + l)      -- P2
// mode 2: out[t][n][col]          (row = n*128 + t)     -- xwx t-major
__global__ __launch_bounds__(256) void k_gemm(const unsigned short* __restrict__ A,
                                              const unsigned short* __restrict__ BT,
                                              const float* __restrict__ bias,
                                              unsigned short* __restrict__ out,
                                              int M, int Nn, int K, int mode) {
    __shared__ unsigned short As[128][40];
    __shared__ unsigned short Bs[128][40];
    int m0 = blockIdx.y * 128, n0 = blockIdx.x * 128;
    int tid = threadIdx.x, lane = tid & 63, wave = tid >> 6;
    int wr = wave >> 1, wc = wave & 1, quad = lane >> 4, l16 = lane & 15;
    f4 acc[4][4];
    #pragma unroll
    for (int i = 0; i < 4; i++)
        #pragma unroll
        for (int j = 0; j < 4; j++) acc[i][j] = f4{0.f, 0.f, 0.f, 0.f};

    for (int k0 = 0; k0 < K; k0 += 32) {
        __syncthreads();
        #pragma unroll
        for (int i = 0; i < 2; i++) {
            int idx = i * 256 + tid, r = idx >> 2, c = idx & 3;
            *(s8v*)&As[r][c * 8] = *(const s8v*)&A[(size_t)(m0 + r) * K + k0 + c * 8];
            *(s8v*)&Bs[r][c * 8] = *(const s8v*)&BT[(size_t)(n0 + r) * K + k0 + c * 8];
        }
        __syncthreads();
        bf8 af[4], bfr[4];
        #pragma unroll
        for (int i = 0; i < 4; i++) af[i] = *(const bf8*)&As[wr * 64 + i * 16 + l16][quad * 8];
        #pragma unroll
        for (int j = 0; j < 4; j++) bfr[j] = *(const bf8*)&Bs[wc * 64 + j * 16 + l16][quad * 8];
        #pragma unroll
        for (int i = 0; i < 4; i++)
            #pragma unroll
            for (int j = 0; j < 4; j++)
                acc[i][j] = __builtin_amdgcn_mfma_f32_16x16x32_bf16(af[i], bfr[j], acc[i][j], 0, 0, 0);
    }

    #pragma unroll
    for (int i = 0; i < 4; i++)
        #pragma unroll
        for (int j = 0; j < 4; j++) {
            int row0 = m0 + wr * 64 + i * 16 + quad * 4;
            int col = n0 + wc * 64 + j * 16 + l16;
            float bia = bias ? bias[col] : 0.0f;
            #pragma unroll
            for (int r = 0; r < 4; r++) {
                float v = acc[i][j][r] + bia;
                int rw = row0 + r;
                if (mode == 0) {
                    out[(size_t)rw * Nn + col] = f2bf(v);
                } else if (mode == 1) {
                    int n = rw >> 4, l = rw & 15;
                    out[((size_t)n * Nn + col) * 16 + l] = f2bf(v);
                } else {
                    int n = rw >> 7, t = rw & 127;
                    out[((size_t)t * 64 + n) * Nn + col] = f2bf(v);
                }
            }
        }
}

// ---------------- persistent recurrent kernel ----------------
// Flags (one 128B line each):
//   hflag[w*32]  w=0..63 : writer gemm wg w=(g*16+c); pollers: 16 siblings
//                          (tid<16) + 4 score wgs (tid<16)
//   wflag[s*32]  s=0..15 : writer score wg s; pollers: 16 gemm wgs of
//                          group s>>2 (tid<4)
__global__ __launch_bounds__(256, 1) void k_recur(
    const float* __restrict__ Afull,
    const unsigned short* __restrict__ WhT, const unsigned short* __restrict__ xwx,
    const unsigned short* __restrict__ P2, const float* __restrict__ cstate,
    unsigned short* __restrict__ hbuf,   // 2 x 65536 bf16 ping-pong
    float* __restrict__ wbuf,            // 64 x 16 f32 softmax weights
    int* __restrict__ wflag, int* __restrict__ hflag,
    float* __restrict__ out) {
    __shared__ unsigned short hLf[16 * 1024];  // 32 KB, XOR-swizzled
    __shared__ float aL[4][16][68];            // 17 KB (stride 68 -> 16B aligned rows)
    __shared__ float wL[256];                  // 16 n x 16 l

    const int wid = blockIdx.x;
    const int tid = threadIdx.x, lane = tid & 63, wave = tid >> 6;
    ull* wbuf_u = (ull*)wbuf;

    if (wid >= 64) {
        // ---------------- score wg: 4 rows, one per wave ----------------
        const int s = wid - 64;         // 0..15
        const int g = s >> 2;           // group
        const int row = s * 4 + wave;   // n in 0..63
        const float* Ab = Afull + ((size_t)row * 1024 + lane * 16) * 16;

        for (int t = 0; t < Tt; ++t) {
            if (tid < 16) {
                while (aldi(&hflag[(g * 16 + tid) * 32]) < t)
                    __builtin_amdgcn_s_sleep(2);
            }
            __syncthreads();
            __builtin_amdgcn_fence(__ATOMIC_ACQUIRE, "workgroup");

            const ull* hb_u = (const ull*)(hbuf + (t & 1) * 65536);
            float hk[16];
            #pragma unroll
            for (int i = 0; i < 4; i++) {
                union { ull u; unsigned short h[4]; } cv;
                cv.u = ald(hb_u + (size_t)row * 256 + lane * 4 + i);
                #pragma unroll
                for (int j = 0; j < 4; j++) hk[i * 4 + j] = bf2f(cv.h[j]);
            }
            float part[16];
            #pragma unroll
            for (int l = 0; l < 16; l++) part[l] = 0.f;
            #pragma unroll
            for (int kk = 0; kk < 16; ++kk) {
                const f4* ar = (const f4*)(Ab + (size_t)kk * 16);
                f4 a0 = ar[0], a1 = ar[1], a2 = ar[2], a3 = ar[3];
                float hv = hk[kk];
                part[0]  += hv * a0.x;  part[1]  += hv * a0.y;
                part[2]  += hv * a0.z;  part[3]  += hv * a0.w;
                part[4]  += hv * a1.x;  part[5]  += hv * a1.y;
                part[6]  += hv * a1.z;  part[7]  += hv * a1.w;
                part[8]  += hv * a2.x;  part[9]  += hv * a2.y;
                part[10] += hv * a2.z;  part[11] += hv * a2.w;
                part[12] += hv * a3.x;  part[13] += hv * a3.y;
                part[14] += hv * a3.z;  part[15] += hv * a3.w;
            }
            #pragma unroll
            for (int l = 0; l < 16; l++) {
                float v = part[l];
                v += __shfl_down(v, 32, 64); v += __shfl_down(v, 16, 64);
                v += __shfl_down(v, 8, 64);  v += __shfl_down(v, 4, 64);
                v += __shfl_down(v, 2, 64);  v += __shfl_down(v, 1, 64);
                part[l] = v;
            }
            if (lane == 0) {
                float sc[16]; float mx = -1e30f;
                #pragma unroll
                for (int l = 0; l < 16; l++) {
                    sc[l] = part[l] * (1.0f / 32.0f);
                    mx = fmaxf(mx, sc[l]);
                }
                float sum = 0.f;
                #pragma unroll
                for (int l = 0; l < 16; l++) { sc[l] = __expf(sc[l] - mx); sum += sc[l]; }
                float inv = 1.0f / sum;
                #pragma unroll
                for (int i = 0; i < 8; i++) {
                    union { ull u; float f[2]; } cv;
                    cv.f[0] = sc[2 * i] * inv; cv.f[1] = sc[2 * i + 1] * inv;
                    ast(wbuf_u + row * 8 + i, cv.u);
                }
            }
            __syncthreads();   // drains wbuf stores (vmcnt 0 at barrier)
            if (tid == 0) asti(&wflag[s * 32], t + 1);
        }
        return;
    }

    // ---------------- gemm wg: group g (16 n), cols c*64..c*64+64 x 4 gates ----
    const int g = wid >> 4, c = wid & 15;
    const int quad = lane >> 4, l16 = lane & 15;
    const int gate = wave;                       // one gate per wave
    const int colb = gate * 1024 + c * 64;       // global WhT col base for wave
    const int swz = (l16 & 7) << 3;              // LDS A swizzle
    // gate/state thread mapping: (n = tid>>4, j-quad = (tid&15)*4)
    const int gn = tid >> 4;
    const int gj = (tid & 15) * 4;
    const int n_glob = g * 16 + gn;
    const int j_glob = c * 64 + gj;

    f4 creg = *(const f4*)&cstate[(size_t)n_glob * 1024 + j_glob];

    for (int t = 0; t < Tt; ++t) {
        const ull* hb_u = (const ull*)(hbuf + (t & 1) * 65536);
        ull* hbW_u = (ull*)(hbuf + ((t + 1) & 1) * 65536);

        // ---- prefetch xwx slab operands (t-major layout) before the wait ----
        unsigned short xw[4][4];
        #pragma unroll
        for (int r = 0; r < 4; r++) {
            int n = g * 16 + quad * 4 + r;
            const unsigned short* xp = xwx + ((size_t)t * 64 + n) * FH + colb + l16;
            #pragma unroll
            for (int j16 = 0; j16 < 4; j16++) xw[r][j16] = xp[j16 * 16];
        }

        // ---- wait for h(t): poll 16 sibling flags directly ----
        if (tid < 16) {
            while (aldi(&hflag[(g * 16 + tid) * 32]) < t)
                __builtin_amdgcn_s_sleep(2);
        }
        __syncthreads();
        __builtin_amdgcn_fence(__ATOMIC_ACQUIRE, "workgroup");

        // ---- stage h(t) group rows (16 x 1024) into swizzled LDS ----
        #pragma unroll
        for (int it = 0; it < 16; ++it) {
            int idx = it * 256 + tid;            // 0..4095 (ull units)
            int r2 = idx >> 8;                   // local row 0..15
            int u8 = idx & 255;                  // ull col
            ull v = ald(hb_u + (((size_t)(g * 16 + r2)) << 8) + u8);
            int es = (u8 * 4) ^ ((r2 & 7) << 3); // elem index, swizzled
            *(ull*)&hLf[r2 * 1024 + es] = v;
        }
        __syncthreads();

        // ---- GEMM: h(16 x 1024) @ Wh-slice(1024 x 64) per wave ----
        f4 acc[4];
        #pragma unroll
        for (int j = 0; j < 4; j++) acc[j] = f4{0.f, 0.f, 0.f, 0.f};
        const unsigned short* hbase = hLf + l16 * 1024;
        #pragma unroll 8
        for (int ks = 0; ks < 32; ++ks) {
            bf8 a = *(const bf8*)&hbase[(quad * 8 + ks * 32) ^ swz];
            #pragma unroll
            for (int j16 = 0; j16 < 4; j16++) {
                bf8 b = *(const bf8*)&WhT[(size_t)(colb + j16 * 16 + l16) * 1024 + quad * 8 + ks * 32];
                acc[j16] = __builtin_amdgcn_mfma_f32_16x16x32_bf16(a, b, acc[j16], 0, 0, 0);
            }
        }

        // ---- softmax weights: poll the group's 4 score flags ----
        if (tid < 4) {
            while (aldi(&wflag[(g * 4 + tid) * 32]) < t + 1)
                __builtin_amdgcn_s_sleep(2);
        }
        __syncthreads();
        __builtin_amdgcn_fence(__ATOMIC_ACQUIRE, "workgroup");
        if (tid < 128) {
            union { ull u; float f[2]; } cv;
            cv.u = ald(wbuf_u + g * 128 + tid);
            wL[tid * 2] = cv.f[0]; wL[tid * 2 + 1] = cv.f[1];
        }
        __syncthreads();

        // ---- epilogue: acc + xwx + attention -> aL[gate][n][j] ----
        #pragma unroll
        for (int j16 = 0; j16 < 4; j16++) {
            int col = colb + j16 * 16 + l16;
            #pragma unroll
            for (int r = 0; r < 4; r++) {
                int nl = quad * 4 + r;
                int n = g * 16 + nl;
                float v = acc[j16][r] + bf2f(xw[r][j16]);
                const unsigned short* pp = P2 + ((size_t)n * FH + col) * 16;
                s8v p0 = *(const s8v*)pp, p1 = *(const s8v*)(pp + 8);
                float sa = 0.f;
                #pragma unroll
                for (int l = 0; l < 8; l++) sa += wL[nl * 16 + l] * bf2f((unsigned short)p0[l]);
                #pragma unroll
                for (int l = 0; l < 8; l++) sa += wL[nl * 16 + 8 + l] * bf2f((unsigned short)p1[l]);
                aL[gate][nl][j16 * 16 + l16] = v + sa;
            }
        }
        __syncthreads();

        // ---- gates: thread owns (n_glob, j_glob..j_glob+4); c in registers ----
        {
            f4 av0 = *(const f4*)&aL[0][gn][gj];
            f4 av1 = *(const f4*)&aL[1][gn][gj];
            f4 av2 = *(const f4*)&aL[2][gn][gj];
            f4 av3 = *(const f4*)&aL[3][gn][gj];
            f4 outv;
            union { ull u; unsigned short h[4]; } pk;
            #pragma unroll
            for (int q = 0; q < 4; q++) {
                float ig = 1.f / (1.f + __expf(-av0[q]));
                float fg = 1.f / (1.f + __expf(-av1[q]));
                float og = 1.f / (1.f + __expf(-av2[q]));
                float gg = tanhf(av3[q]);
                creg[q] = fg * creg[q] + ig * gg;
                float hv = og * tanhf(creg[q]);
                outv[q] = hv;
                pk.h[q] = f2bf(hv);
            }
            *(f4*)&out[((size_t)n_glob * Tt + t) * 1024 + j_glob] = outv;
            if (t < Tt - 1) {
                ast(hbW_u + ((size_t)n_glob << 8) + (j_glob >> 2), pk.u);
            }
        }

        // ---- publish flag: barrier drains vmcnt; relaxed flag ----
        if (t < Tt - 1) {
            __syncthreads();
            if (tid == 0) asti(&hflag[wid * 32], t + 1);
        }
    }
}

// ---------------- launch ----------------

extern "C" void kernel_launch(void* const* d_in, const int* in_sizes, int n_in,
                              void* d_out, int out_size, void* d_ws, size_t ws_size,
                              hipStream_t stream) {
    const float* x     = (const float*)d_in[0];   // [64][128][512]
    const float* A     = (const float*)d_in[1];   // [64][1024][16]
    const float* Wx    = (const float*)d_in[2];   // [512][4096]
    const float* Wh    = (const float*)d_in[3];   // [1024][4096]
    const float* Wattn = (const float*)d_in[4];   // [1024][4096]
    const float* b     = (const float*)d_in[5];   // [4096]
    float* out = (float*)d_out;
    char* ws = (char*)d_ws;

    unsigned short* xbf    = (unsigned short*)(ws);                // 8 MB; reused for P2
    unsigned short* P2     = (unsigned short*)(ws);                // alias (xbf dead by then)
    unsigned short* WxT    = (unsigned short*)(ws + 8388608);      // 4 MB
    unsigned short* WhT    = (unsigned short*)(ws + 12582912);     // 8 MB
    unsigned short* WattnT = (unsigned short*)(ws + 20971520);     // 8 MB
    unsigned short* Afl    = (unsigned short*)(ws + 29360128);     // 2 MB
    unsigned short* xwx    = (unsigned short*)(ws + 31457280);     // 64 MB (t-major)
    float* cstate          = (float*)(ws + 98566144);              // 256 KB
    unsigned short* hbuf   = (unsigned short*)(ws + 98828288);     // 256 KB (2x ping-pong)
    float* wbuf            = (float*)(ws + 99090432);              // 4 KB
    int* hflag             = (int*)(ws + 99094528);                // 8 KB (64 lines)
    int* wflag             = (int*)(ws + 99127296);                // 2 KB (16 lines)

    (void)hipMemsetAsync(ws + 99094528, 0, 65536, stream);         // all flags

    k_cast_bf16<<<16384, 256, 0, stream>>>(x, xbf, 4194304);
    k_transpose_bf16<<<dim3(128, 16), 256, 0, stream>>>(Wx, WxT, 512);
    k_transpose_bf16<<<dim3(128, 32), 256, 0, stream>>>(Wh, WhT, 1024);
    k_transpose_bf16<<<dim3(128, 32), 256, 0, stream>>>(Wattn, WattnT, 1024);
    k_afl<<<4096, 256, 0, stream>>>(A, Afl);
    k_init<<<256, 256, 0, stream>>>(A, cstate, hbuf);

    k_gemm<<<dim3(32, 64), 256, 0, stream>>>(xbf, WxT, b, xwx, 8192, 4096, 512, 2);
    k_gemm<<<dim3(32, 8), 256, 0, stream>>>(Afl, WattnT, nullptr, P2, 1024, 4096, 1024, 1);

    k_recur<<<80, 256, 0, stream>>>(A, WhT, xwx, P2, cstate, hbuf, wbuf,
                                    wflag, hflag, out);
}

// Round 3
// 1226.361 us; speedup vs baseline: 3.1676x; 3.1676x over previous
//
#include <hip/hip_runtime.h>
#include <stdint.h>

// N=64, T=128, D=512, H=1024, 4H=4096.
// R8: data-path attack (R6 ruled out poll contention; R7 showed unhidden
// global B loads + 1 wave/SIMD is fatal):
//   - Wh PERSISTENT IN LDS: 256 wgs x 512 thr; wg owns 8 h-cols x 4 gates
//     (32 acols x K=1024 = 64 KB), loaded once. K-loop is pure LDS
//     (XOR-swizzled, conflict-free-ish ds_read_b128).
//   - h ring buffer depth 32 (4 MB, over dead WattnT region): producers
//     agent write-through stores (LLC fresh), consumers PLAIN CACHED loads
//     (first-touch per launch; >90MB L2 traffic between slot reuse;
//     end-of-kernel invalidate covers cross-launch).
//   - score duty folded into gemm wgs (C<8): waves 4..7 (idle during GEMM)
//     compute 4 softmax rows from the already-staged LDS h tile + bf16 Afl,
//     IN PARALLEL with the 4 GEMM waves. Grid = 256 exactly, 1 wg/CU.
//   - fan-in flat: 128 sibling h-flags polled by 128 threads; 8 w-flags.
// Ordering discipline unchanged: relaxed agent data stores -> __syncthreads
// (vmcnt drain) -> relaxed flag; workgroup acquire fence on consume.

#define Tt 128
#define FH 4096
#define RING_D 32

typedef __bf16 bf8 __attribute__((ext_vector_type(8)));
typedef float f4 __attribute__((ext_vector_type(4)));
typedef short s8v __attribute__((ext_vector_type(8)));
typedef unsigned long long ull;

__device__ __forceinline__ float bf2f(unsigned short u) {
    union { unsigned u32; float f; } x; x.u32 = ((unsigned)u) << 16; return x.f;
}
__device__ __forceinline__ unsigned short f2bf(float f) {
    union { float f32; unsigned u; } x; x.f32 = f;
    unsigned r = x.u + 0x7fffu + ((x.u >> 16) & 1u);
    return (unsigned short)(r >> 16);
}
__device__ __forceinline__ ull ald(const ull* p) {
    return __hip_atomic_load((ull*)p, __ATOMIC_RELAXED, __HIP_MEMORY_SCOPE_AGENT);
}
__device__ __forceinline__ void ast(ull* p, ull v) {
    __hip_atomic_store(p, v, __ATOMIC_RELAXED, __HIP_MEMORY_SCOPE_AGENT);
}
__device__ __forceinline__ int aldi(const int* p) {
    return __hip_atomic_load((int*)p, __ATOMIC_RELAXED, __HIP_MEMORY_SCOPE_AGENT);
}
__device__ __forceinline__ void asti(int* p, int v) {
    __hip_atomic_store(p, v, __ATOMIC_RELAXED, __HIP_MEMORY_SCOPE_AGENT);
}
__device__ __forceinline__ void astf(float* p, float v) {
    __hip_atomic_store(p, v, __ATOMIC_RELAXED, __HIP_MEMORY_SCOPE_AGENT);
}

// ---------------- converts / init ----------------

__global__ __launch_bounds__(256) void k_cast_bf16(const float* __restrict__ in,
                                                   unsigned short* __restrict__ out, int n) {
    int i = blockIdx.x * 256 + threadIdx.x;
    if (i < n) out[i] = f2bf(in[i]);
}

__global__ __launch_bounds__(256) void k_transpose_bf16(const float* __restrict__ W,
                                                        unsigned short* __restrict__ WT, int K) {
    __shared__ float tl[32][33];
    int c0 = blockIdx.x * 32, k0 = blockIdx.y * 32;
    int tx = threadIdx.x & 31, ty = threadIdx.x >> 5;
    #pragma unroll
    for (int i = 0; i < 32; i += 8) tl[ty + i][tx] = W[(size_t)(k0 + ty + i) * 4096 + c0 + tx];
    __syncthreads();
    #pragma unroll
    for (int i = 0; i < 32; i += 8) WT[(size_t)(c0 + ty + i) * K + k0 + tx] = f2bf(tl[tx][ty + i]);
}

__global__ __launch_bounds__(256) void k_afl(const float* __restrict__ A,
                                             unsigned short* __restrict__ Afl) {
    int idx = blockIdx.x * 256 + threadIdx.x;
    int k = idx & 1023, l = (idx >> 10) & 15, n = idx >> 14;
    Afl[idx] = f2bf(A[((size_t)n * 1024 + k) * 16 + l]);   // Afl[n][l][k]
}

__global__ __launch_bounds__(256) void k_init(const float* __restrict__ A,
                                              float* __restrict__ cstate,
                                              unsigned short* __restrict__ ring0) {
    int idx = blockIdx.x * 256 + threadIdx.x;   // 64*1024
    const float* ap = A + (size_t)idx * 16;
    float s = 0.f;
    #pragma unroll
    for (int l = 0; l < 16; l++) s += ap[l];
    float h = s * (1.0f / 16.0f);
    cstate[idx] = h;
    ring0[idx] = f2bf(h);
}

// ---------------- generic bf16 MFMA GEMM (preamble) ----------------
// mode 0: out[row][col]; mode 1: out[n][col][l] (row=n*16+l) -- P2
// mode 2: out[t][n][col] (row=n*128+t)                        -- xwx t-major
__global__ __launch_bounds__(256) void k_gemm(const unsigned short* __restrict__ A,
                                              const unsigned short* __restrict__ BT,
                                              const float* __restrict__ bias,
                                              unsigned short* __restrict__ out,
                                              int M, int Nn, int K, int mode) {
    __shared__ unsigned short As[128][40];
    __shared__ unsigned short Bs[128][40];
    int m0 = blockIdx.y * 128, n0 = blockIdx.x * 128;
    int tid = threadIdx.x, lane = tid & 63, wave = tid >> 6;
    int wr = wave >> 1, wc = wave & 1, quad = lane >> 4, l16 = lane & 15;
    f4 acc[4][4];
    #pragma unroll
    for (int i = 0; i < 4; i++)
        #pragma unroll
        for (int j = 0; j < 4; j++) acc[i][j] = f4{0.f, 0.f, 0.f, 0.f};

    for (int k0 = 0; k0 < K; k0 += 32) {
        __syncthreads();
        #pragma unroll
        for (int i = 0; i < 2; i++) {
            int idx = i * 256 + tid, r = idx >> 2, c = idx & 3;
            *(s8v*)&As[r][c * 8] = *(const s8v*)&A[(size_t)(m0 + r) * K + k0 + c * 8];
            *(s8v*)&Bs[r][c * 8] = *(const s8v*)&BT[(size_t)(n0 + r) * K + k0 + c * 8];
        }
        __syncthreads();
        bf8 af[4], bfr[4];
        #pragma unroll
        for (int i = 0; i < 4; i++) af[i] = *(const bf8*)&As[wr * 64 + i * 16 + l16][quad * 8];
        #pragma unroll
        for (int j = 0; j < 4; j++) bfr[j] = *(const bf8*)&Bs[wc * 64 + j * 16 + l16][quad * 8];
        #pragma unroll
        for (int i = 0; i < 4; i++)
            #pragma unroll
            for (int j = 0; j < 4; j++)
                acc[i][j] = __builtin_amdgcn_mfma_f32_16x16x32_bf16(af[i], bfr[j], acc[i][j], 0, 0, 0);
    }

    #pragma unroll
    for (int i = 0; i < 4; i++)
        #pragma unroll
        for (int j = 0; j < 4; j++) {
            int row0 = m0 + wr * 64 + i * 16 + quad * 4;
            int col = n0 + wc * 64 + j * 16 + l16;
            float bia = bias ? bias[col] : 0.0f;
            #pragma unroll
            for (int r = 0; r < 4; r++) {
                float v = acc[i][j][r] + bia;
                int rw = row0 + r;
                if (mode == 0) {
                    out[(size_t)rw * Nn + col] = f2bf(v);
                } else if (mode == 1) {
                    int n = rw >> 4, l = rw & 15;
                    out[((size_t)n * Nn + col) * 16 + l] = f2bf(v);
                } else {
                    int n = rw >> 7, t = rw & 127;
                    out[((size_t)t * 64 + n) * Nn + col] = f2bf(v);
                }
            }
        }
}

// ---------------- persistent recurrent kernel ----------------
// 256 wgs x 512 thr. wg = (R = wid>>7: n-group of 32 rows, C = wid&127:
// 8 h-cols x 4 gates = 32 acols). Waves 0..3: GEMM tiles (ntile, ctile).
// Waves 4..7: score duty (C<8 only): softmax rows C*4+(wave-4).
// Flags: hflag[w*32] w=0..255 (writer wg w, pollers: 128 same-R wgs);
//        wflag[s*32] s=0..15 (writer wg R*128+C(C<8), pollers same-R wgs).
__global__ __launch_bounds__(512, 2) void k_recur(
    const unsigned short* __restrict__ Afl,
    const unsigned short* __restrict__ WhT, const unsigned short* __restrict__ xwx,
    const unsigned short* __restrict__ P2, const float* __restrict__ cstate,
    unsigned short* __restrict__ ring,   // [32][64][1024] bf16
    float* __restrict__ wbuf,            // 64 x 16 f32 softmax weights
    int* __restrict__ wflag, int* __restrict__ hflag,
    float* __restrict__ out) {
    __shared__ unsigned short WhS[32][1024];   // 64 KB, persistent, swizzled
    __shared__ unsigned short hS[32][1024];    // 64 KB, per-step, swizzled
    __shared__ float aL[32][36];               // 4.6 KB
    __shared__ float wL[512];                  // 2 KB  (32 n x 16 l)
    __shared__ unsigned short hpk[32][8];      // 0.5 KB

    const int wid = blockIdx.x;               // 0..255
    const int R = wid >> 7, C = wid & 127;
    const int tid = threadIdx.x, lane = tid & 63, wave = tid >> 6;
    const int l16 = lane & 15, quad = lane >> 4;
    ull* wbuf_u = (ull*)wbuf;

    // GEMM tile assignment (waves 0..3)
    const int ntile = wave & 1, ctile = (wave >> 1) & 1;
    // epilogue/gate mapping (tid<256): (n_l, j)
    const int n_l = tid >> 3, j = tid & 7;
    const int n_glob = R * 32 + n_l;
    const int jcol = C * 8 + j;
    // score duty (waves 4..7, C<8)
    const bool sduty = (C < 8) && (wave >= 4);
    const int srow_l = C * 4 + (wave - 4);     // local row 0..31
    const int sn = R * 32 + srow_l;

    // ---- load Wh slice into LDS once (rows al=q*8+jj -> acol q*1024+C*8+jj)
    for (int c = tid; c < 4096; c += 512) {    // 16B chunks
        int row = c >> 7, pos = c & 127;
        int q = row >> 3, jj = row & 7;
        int acolg = q * 1024 + C * 8 + jj;
        s8v v = *(const s8v*)&WhT[(size_t)acolg * 1024 + pos * 8];
        int e = (pos * 8) ^ ((row & 7) << 3);
        *(s8v*)&WhS[row][e] = v;
    }

    float creg = (tid < 256) ? cstate[(size_t)n_glob * 1024 + jcol] : 0.f;

    __syncthreads();

    for (int t = 0; t < Tt; ++t) {
        const unsigned short* rg = ring + (size_t)(t & (RING_D - 1)) * 65536;
        unsigned short* rw = ring + (size_t)((t + 1) & (RING_D - 1)) * 65536;

        // ---- prefetch epilogue operands (plain cached loads) ----
        unsigned short xwr[4];
        s8v p2r[4][2];
        if (tid < 256) {
            const unsigned short* xp = xwx + ((size_t)t * 64 + n_glob) * FH;
            #pragma unroll
            for (int q = 0; q < 4; q++) {
                int ac = q * 1024 + jcol;
                xwr[q] = xp[ac];
                const unsigned short* pp = P2 + ((size_t)n_glob * FH + ac) * 16;
                p2r[q][0] = *(const s8v*)pp;
                p2r[q][1] = *(const s8v*)(pp + 8);
            }
        }

        // ---- wait for h(t): 128 threads poll 128 same-R producer flags ----
        if (t > 0 && tid < 128) {
            while (aldi(&hflag[(R * 128 + tid) * 32]) < t)
                __builtin_amdgcn_s_sleep(2);
        }
        __syncthreads();
        __builtin_amdgcn_fence(__ATOMIC_ACQUIRE, "workgroup");

        // ---- stage h(t) R-half (32 x 1024) into swizzled LDS (cached loads)
        #pragma unroll
        for (int it = 0; it < 8; ++it) {
            int c = it * 512 + tid;            // 16B chunk 0..4095
            int row = c >> 7, pos = c & 127;
            s8v v = *(const s8v*)&rg[((size_t)(R * 32 + row)) * 1024 + pos * 8];
            int e = (pos * 8) ^ ((row & 7) << 3);
            *(s8v*)&hS[row][e] = v;
        }
        __syncthreads();

        // ---- waves 0..3: GEMM 32x32 over K=1024 (pure LDS) ----
        if (wave < 4) {
            const int arow = ntile * 16 + l16;
            const int brow = ctile * 16 + l16;
            const int aswz = (arow & 7) << 3, bswz = (brow & 7) << 3;
            const int kb = quad * 8;
            f4 acc = {0.f, 0.f, 0.f, 0.f};
            #pragma unroll 8
            for (int ks = 0; ks < 32; ++ks) {
                bf8 a = *(const bf8*)&hS[arow][(kb + ks * 32) ^ aswz];
                bf8 b = *(const bf8*)&WhS[brow][(kb + ks * 32) ^ bswz];
                acc = __builtin_amdgcn_mfma_f32_16x16x32_bf16(a, b, acc, 0, 0, 0);
            }
            #pragma unroll
            for (int r = 0; r < 4; r++)
                aL[ntile * 16 + quad * 4 + r][ctile * 16 + l16] = acc[r];
        } else if (sduty) {
            // ---- waves 4..7 (C<8): score row sn from LDS h + bf16 Afl ----
            const int sl = lane & 15, kg = lane >> 4;   // l, k-group (256 k)
            const int swz = (srow_l & 7) << 3;
            const unsigned short* ap = Afl + ((size_t)sn * 16 + sl) * 1024 + kg * 256;
            float psum = 0.f;
            #pragma unroll 8
            for (int kc = 0; kc < 32; ++kc) {           // 8-elem chunks
                int kbase = kg * 256 + kc * 8;
                s8v hv = *(const s8v*)&hS[srow_l][kbase ^ swz];
                s8v av = *(const s8v*)&ap[kc * 8];
                #pragma unroll
                for (int e2 = 0; e2 < 8; e2++)
                    psum = fmaf(bf2f((unsigned short)hv[e2]),
                                bf2f((unsigned short)av[e2]), psum);
            }
            psum += __shfl_xor(psum, 16, 64);
            psum += __shfl_xor(psum, 32, 64);
            float sc = psum * (1.0f / 32.0f);
            float mx = sc;
            mx = fmaxf(mx, __shfl_xor(mx, 1, 64));
            mx = fmaxf(mx, __shfl_xor(mx, 2, 64));
            mx = fmaxf(mx, __shfl_xor(mx, 4, 64));
            mx = fmaxf(mx, __shfl_xor(mx, 8, 64));
            float ev = __expf(sc - mx);
            float sum = ev;
            sum += __shfl_xor(sum, 1, 64);
            sum += __shfl_xor(sum, 2, 64);
            sum += __shfl_xor(sum, 4, 64);
            sum += __shfl_xor(sum, 8, 64);
            float w = ev / sum;
            if (lane < 16) astf(&wbuf[sn * 16 + sl], w);
        }
        __syncthreads();   // aL ready; wbuf stores drained (vmcnt 0)
        if (C < 8 && tid == 0) asti(&wflag[(R * 8 + C) * 32], t + 1);

        // ---- w wait + load to LDS ----
        if (tid < 8) {
            while (aldi(&wflag[(R * 8 + tid) * 32]) < t + 1)
                __builtin_amdgcn_s_sleep(2);
        }
        __syncthreads();
        __builtin_amdgcn_fence(__ATOMIC_ACQUIRE, "workgroup");
        if (tid < 256) {
            union { ull u; float f[2]; } cv;
            cv.u = ald(wbuf_u + (size_t)R * 256 + tid);
            wL[tid * 2] = cv.f[0]; wL[tid * 2 + 1] = cv.f[1];
        }
        __syncthreads();

        // ---- epilogue + gates (tid<256): thread owns (n_glob, jcol) ----
        if (tid < 256) {
            float av4[4];
            #pragma unroll
            for (int q = 0; q < 4; q++) {
                int al = q * 8 + j;
                float v = aL[n_l][al] + bf2f(xwr[q]);
                float sa = 0.f;
                #pragma unroll
                for (int l = 0; l < 8; l++)
                    sa = fmaf(wL[n_l * 16 + l], bf2f((unsigned short)p2r[q][0][l]), sa);
                #pragma unroll
                for (int l = 0; l < 8; l++)
                    sa = fmaf(wL[n_l * 16 + 8 + l], bf2f((unsigned short)p2r[q][1][l]), sa);
                av4[q] = v + sa;
            }
            float ig = 1.f / (1.f + __expf(-av4[0]));
            float fg = 1.f / (1.f + __expf(-av4[1]));
            float og = 1.f / (1.f + __expf(-av4[2]));
            float gg = tanhf(av4[3]);
            creg = fg * creg + ig * gg;
            float hv = og * tanhf(creg);
            out[((size_t)n_glob * Tt + t) * 1024 + jcol] = hv;
            hpk[n_l][j] = f2bf(hv);
        }
        __syncthreads();

        // ---- publish h(t+1) chunk (agent write-through) + flag ----
        if (t < Tt - 1) {
            if (tid < 64) {
                int row = tid >> 1, half = tid & 1;
                ull v = *(const ull*)&hpk[row][half * 4];
                ast((ull*)rw + ((size_t)(R * 32 + row) << 8) + C * 2 + half, v);
            }
            __syncthreads();   // drains vmcnt for ring stores
            if (tid == 0) asti(&hflag[wid * 32], t + 1);
        }
    }
}

// ---------------- launch ----------------

extern "C" void kernel_launch(void* const* d_in, const int* in_sizes, int n_in,
                              void* d_out, int out_size, void* d_ws, size_t ws_size,
                              hipStream_t stream) {
    const float* x     = (const float*)d_in[0];   // [64][128][512]
    const float* A     = (const float*)d_in[1];   // [64][1024][16]
    const float* Wx    = (const float*)d_in[2];   // [512][4096]
    const float* Wh    = (const float*)d_in[3];   // [1024][4096]
    const float* Wattn = (const float*)d_in[4];   // [1024][4096]
    const float* b     = (const float*)d_in[5];   // [4096]
    float* out = (float*)d_out;
    char* ws = (char*)d_ws;

    unsigned short* xbf    = (unsigned short*)(ws);                // 8 MB; reused for P2
    unsigned short* P2     = (unsigned short*)(ws);                // alias (xbf dead by then)
    unsigned short* WxT    = (unsigned short*)(ws + 8388608);      // 4 MB
    unsigned short* WhT    = (unsigned short*)(ws + 12582912);     // 8 MB
    unsigned short* WattnT = (unsigned short*)(ws + 20971520);     // 8 MB (dead after P2 gemm)
    unsigned short* ring   = (unsigned short*)(ws + 20971520);     // 4 MB ring, over dead WattnT
    unsigned short* Afl    = (unsigned short*)(ws + 29360128);     // 2 MB
    unsigned short* xwx    = (unsigned short*)(ws + 31457280);     // 64 MB (t-major)
    float* cstate          = (float*)(ws + 98566144);              // 256 KB
    float* wbuf            = (float*)(ws + 99090432);              // 4 KB
    int* hflag             = (int*)(ws + 99094528);                // 32 KB (256 lines)
    int* wflag             = (int*)(ws + 99127296);                // 2 KB (16 lines)

    (void)hipMemsetAsync(ws + 99094528, 0, 36864, stream);         // all flags

    k_cast_bf16<<<16384, 256, 0, stream>>>(x, xbf, 4194304);
    k_transpose_bf16<<<dim3(128, 16), 256, 0, stream>>>(Wx, WxT, 512);
    k_transpose_bf16<<<dim3(128, 32), 256, 0, stream>>>(Wh, WhT, 1024);
    k_transpose_bf16<<<dim3(128, 32), 256, 0, stream>>>(Wattn, WattnT, 1024);
    k_afl<<<4096, 256, 0, stream>>>(A, Afl);

    k_gemm<<<dim3(32, 64), 256, 0, stream>>>(xbf, WxT, b, xwx, 8192, 4096, 512, 2);
    k_gemm<<<dim3(32, 8), 256, 0, stream>>>(Afl, WattnT, nullptr, P2, 1024, 4096, 1024, 1);

    // k_init AFTER the gemms: ring slot 0 lives over the (now dead) WattnT
    k_init<<<256, 256, 0, stream>>>(A, cstate, ring);

    k_recur<<<256, 512, 0, stream>>>(Afl, WhT, xwx, P2, cstate, ring, wbuf,
                                     wflag, hflag, out);
}